// Round 8
// baseline (335.681 us; speedup 1.0000x reference)
//
#include <hip/hip_runtime.h>
#include <math.h>

#define NCLASS 40
#define BEDG 1024
#define CAP 24576  // LDS col-staging capacity per 512-node sub-bucket

typedef float f32x4 __attribute__((ext_vector_type(4)));
typedef float f32x2 __attribute__((ext_vector_type(2)));
typedef __bf16 bf16x8 __attribute__((ext_vector_type(8)));

typedef __attribute__((address_space(1))) const void gv_t;
typedef __attribute__((address_space(3))) void lv_t;
#define GLOAD_LDS16(g, l) __builtin_amdgcn_global_load_lds((gv_t*)(g), (lv_t*)(l), 16, 0, 0)
#define NTL(p) __builtin_nontemporal_load(p)

__device__ inline unsigned short f2bf(float f) {
  unsigned u = __float_as_uint(f);
  unsigned r = (u + 0x7fff + ((u >> 16) & 1)) >> 16;
  return (unsigned short)r;
}
__device__ inline float bflo(unsigned v) { return __uint_as_float(v << 16); }
__device__ inline float bfhi(unsigned v) { return __uint_as_float(v & 0xffff0000u); }
__device__ inline unsigned char f2fp8(float v) {
  return (unsigned char)(__builtin_amdgcn_cvt_pk_fp8_f32(v, v, 0, false) & 0xff);
}

// decode 16 fp8 (one uint4) and accumulate with scale
#define ACCQ(u, sc)                                                                  \
  do {                                                                               \
    f32x2 p_;                                                                        \
    p_ = __builtin_amdgcn_cvt_pk_f32_fp8(u.x, false);                                \
    acc[0] = fmaf(p_.x, sc, acc[0]); acc[1] = fmaf(p_.y, sc, acc[1]);                \
    p_ = __builtin_amdgcn_cvt_pk_f32_fp8(u.x, true);                                 \
    acc[2] = fmaf(p_.x, sc, acc[2]); acc[3] = fmaf(p_.y, sc, acc[3]);                \
    p_ = __builtin_amdgcn_cvt_pk_f32_fp8(u.y, false);                                \
    acc[4] = fmaf(p_.x, sc, acc[4]); acc[5] = fmaf(p_.y, sc, acc[5]);                \
    p_ = __builtin_amdgcn_cvt_pk_f32_fp8(u.y, true);                                 \
    acc[6] = fmaf(p_.x, sc, acc[6]); acc[7] = fmaf(p_.y, sc, acc[7]);                \
    p_ = __builtin_amdgcn_cvt_pk_f32_fp8(u.z, false);                                \
    acc[8] = fmaf(p_.x, sc, acc[8]); acc[9] = fmaf(p_.y, sc, acc[9]);                \
    p_ = __builtin_amdgcn_cvt_pk_f32_fp8(u.z, true);                                 \
    acc[10] = fmaf(p_.x, sc, acc[10]); acc[11] = fmaf(p_.y, sc, acc[11]);            \
    p_ = __builtin_amdgcn_cvt_pk_f32_fp8(u.w, false);                                \
    acc[12] = fmaf(p_.x, sc, acc[12]); acc[13] = fmaf(p_.y, sc, acc[13]);            \
    p_ = __builtin_amdgcn_cvt_pk_f32_fp8(u.w, true);                                 \
    acc[14] = fmaf(p_.x, sc, acc[14]); acc[15] = fmaf(p_.y, sc, acc[15]);            \
  } while (0)

// ================= CSR build: two-level atomic-free counting sort =============
__global__ void k_bcount(const int* __restrict__ dst, int E, int PART,
                         int* __restrict__ bcnt) {
  __shared__ int lc[8];
  int k = blockIdx.x;
  if (threadIdx.x < 8) lc[threadIdx.x] = 0;
  __syncthreads();
  int lo = k * BEDG, hi = min(lo + BEDG, E);
  for (int i = lo + threadIdx.x; i < hi; i += blockDim.x)
    atomicAdd(&lc[NTL(&dst[i]) / PART], 1);
  __syncthreads();
  if (threadIdx.x < 8) bcnt[k * 8 + threadIdx.x] = lc[threadIdx.x];
}

__global__ void k_bscanA(int* __restrict__ bcnt, int nbB, int* __restrict__ btot) {
  __shared__ int tmp[256];
  __shared__ int carryS;
  int b = blockIdx.x;
  int tid = threadIdx.x;
  if (tid == 0) carryS = 0;
  __syncthreads();
  for (int c0 = 0; c0 < nbB; c0 += 256) {
    int idx = c0 + tid;
    int v = (idx < nbB) ? bcnt[idx * 8 + b] : 0;
    tmp[tid] = v;
    __syncthreads();
    for (int d = 1; d < 256; d <<= 1) {
      int t = (tid >= d) ? tmp[tid - d] : 0;
      __syncthreads();
      tmp[tid] += t;
      __syncthreads();
    }
    if (idx < nbB) bcnt[idx * 8 + b] = carryS + tmp[tid] - v;
    __syncthreads();
    if (tid == 255) carryS += tmp[255];
    __syncthreads();
  }
  if (tid == 0) btot[b] = carryS;
}

__global__ void k_bbase(const int* __restrict__ btot, int* __restrict__ bbase) {
  if (threadIdx.x == 0) {
    int s = 0;
    for (int b = 0; b < 8; ++b) {
      bbase[b] = s;
      s += btot[b];
    }
    bbase[8] = s;
  }
}

__global__ void k_place(const int* __restrict__ dst, const int* __restrict__ src, int E,
                        int PART, const int* __restrict__ bcnt,
                        const int* __restrict__ bbase, int* __restrict__ ebuf) {
  __shared__ int lbase[8];
  __shared__ int lcnt[8];
  int k = blockIdx.x;
  if (threadIdx.x < 8) {
    lbase[threadIdx.x] = bbase[threadIdx.x] + bcnt[k * 8 + threadIdx.x];
    lcnt[threadIdx.x] = 0;
  }
  __syncthreads();
  int lo = k * BEDG, hi = min(lo + BEDG, E);
  for (int i = lo + threadIdx.x; i < hi; i += blockDim.x) {
    int d = NTL(&dst[i]);
    int s = NTL(&src[i]);
    int p = d / PART;
    int r = atomicAdd(&lcnt[p], 1);
    ebuf[lbase[p] + r] = (int)(((unsigned)(d - p * PART) << 17) | (unsigned)s);
  }
}

__global__ void k_bcount2(const int* __restrict__ ebuf, const int* __restrict__ bbase,
                          int CB, int* __restrict__ bcnt2) {
  __shared__ int lc[32];
  int p = blockIdx.x & 7, j = blockIdx.x >> 3;
  int tid = threadIdx.x;
  if (tid < 32) lc[tid] = 0;
  __syncthreads();
  int lo = bbase[p], hi = bbase[p + 1];
  for (int base = lo + j * BEDG; base < hi; base += CB * BEDG) {
    int end = min(base + BEDG, hi);
    for (int i = base + tid; i < end; i += 256)
      atomicAdd(&lc[(((unsigned)NTL(&ebuf[i])) >> 17) >> 9], 1);
  }
  __syncthreads();
  if (tid < 32) bcnt2[(p * CB + j) * 32 + tid] = lc[tid];
}

__global__ void k_bscan2(int* __restrict__ bcnt2, int CB, int* __restrict__ tot2) {
  __shared__ int tmp[256];
  int p = blockIdx.x >> 5, k = blockIdx.x & 31;
  int tid = threadIdx.x;
  int v = (tid < CB) ? bcnt2[(p * CB + tid) * 32 + k] : 0;
  tmp[tid] = v;
  __syncthreads();
  for (int d = 1; d < 256; d <<= 1) {
    int t = (tid >= d) ? tmp[tid - d] : 0;
    __syncthreads();
    tmp[tid] += t;
    __syncthreads();
  }
  if (tid < CB) bcnt2[(p * CB + tid) * 32 + k] = tmp[tid] - v;
  if (tid == 255) tot2[p * 32 + k] = tmp[255];
}

__global__ void k_base2(const int* __restrict__ bbase, const int* __restrict__ tot2,
                        int* __restrict__ base2) {
  int p = threadIdx.x;
  if (p >= 8) return;
  int s = bbase[p];
  for (int k = 0; k < 32; ++k) {
    base2[p * 32 + k] = s;
    s += tot2[p * 32 + k];
  }
}

__global__ void k_place2(const int* __restrict__ ebuf, const int* __restrict__ bbase,
                         const int* __restrict__ bcnt2, const int* __restrict__ base2,
                         int CB, int* __restrict__ ebuf2) {
  __shared__ int lb[32];
  int p = blockIdx.x & 7, j = blockIdx.x >> 3;
  int tid = threadIdx.x;
  if (tid < 32) lb[tid] = base2[p * 32 + tid] + bcnt2[(p * CB + j) * 32 + tid];
  __syncthreads();
  int lo = bbase[p], hi = bbase[p + 1];
  for (int base = lo + j * BEDG; base < hi; base += CB * BEDG) {
    int end = min(base + BEDG, hi);
    for (int i = base + tid; i < end; i += 256) {
      unsigned pk = (unsigned)NTL(&ebuf[i]);
      int pos = atomicAdd(&lb[(pk >> 17) >> 9], 1);
      ebuf2[pos] = (int)pk;
    }
  }
}

__global__ __launch_bounds__(256) void k_csr(const int* __restrict__ ebuf2,
                                             const int* __restrict__ base2,
                                             const int* __restrict__ tot2, int PART,
                                             int N, int E, int* __restrict__ off,
                                             int* __restrict__ col) {
  __shared__ int cnt[512];
  __shared__ int cur[512];
  __shared__ int tmp[256];
  __shared__ int stage[CAP];
  int p = blockIdx.x & 7, k = blockIdx.x >> 3;
  int tid = threadIdx.x;
  if (p == 0 && k == 0 && tid == 0) off[N] = E;
  int n0l = k << 9;
  if (n0l >= PART) return;
  int node0 = p * PART + n0l;
  if (node0 >= N) return;
  int nn = min(512, PART - n0l);
  nn = min(nn, N - node0);
  int lo = base2[p * 32 + k];
  int tot = tot2[p * 32 + k];

  cnt[tid] = 0;
  cnt[tid + 256] = 0;
  __syncthreads();
  for (int i = lo + tid; i < lo + tot; i += 256)
    atomicAdd(&cnt[(((unsigned)ebuf2[i]) >> 17) & 511], 1);
  __syncthreads();

  int v0 = cnt[2 * tid], v1 = cnt[2 * tid + 1];
  int s = v0 + v1;
  tmp[tid] = s;
  __syncthreads();
  for (int d = 1; d < 256; d <<= 1) {
    int t = (tid >= d) ? tmp[tid - d] : 0;
    __syncthreads();
    tmp[tid] += t;
    __syncthreads();
  }
  int excl = tmp[tid] - s;
  cnt[2 * tid] = excl;
  cnt[2 * tid + 1] = excl + v0;
  cur[2 * tid] = excl;
  cur[2 * tid + 1] = excl + v0;
  __syncthreads();

  for (int i = tid; i < nn; i += 256) off[node0 + i] = lo + cnt[i];

  if (tot <= CAP) {
    for (int i = lo + tid; i < lo + tot; i += 256) {
      unsigned pk = (unsigned)ebuf2[i];
      int pos = atomicAdd(&cur[(pk >> 17) & 511], 1);
      stage[pos] = (int)(pk & 0x1FFFFu);
    }
    __syncthreads();
    for (int i = tid; i < tot; i += 256) col[lo + i] = stage[i];
  } else {
    for (int i = lo + tid; i < lo + tot; i += 256) {
      unsigned pk = (unsigned)ebuf2[i];
      int pos = atomicAdd(&cur[(pk >> 17) & 511], 1);
      col[lo + pos] = (int)(pk & 0x1FFFFu);
    }
  }
}

// ---------------- casts / weight prep ----------------
__global__ void k_cast(const float4* __restrict__ x, uint4* __restrict__ xb,
                       uint2* __restrict__ xq, int n8) {
  int i = blockIdx.x * blockDim.x + threadIdx.x;
  if (i >= n8) return;
  float4 a = x[i * 2], b = x[i * 2 + 1];
  uint4 o;
  o.x = (unsigned)f2bf(a.x) | ((unsigned)f2bf(a.y) << 16);
  o.y = (unsigned)f2bf(a.z) | ((unsigned)f2bf(a.w) << 16);
  o.z = (unsigned)f2bf(b.x) | ((unsigned)f2bf(b.y) << 16);
  o.w = (unsigned)f2bf(b.z) | ((unsigned)f2bf(b.w) << 16);
  xb[i] = o;
  unsigned lo = __builtin_amdgcn_cvt_pk_fp8_f32(a.x, a.y, 0, false);
  lo = __builtin_amdgcn_cvt_pk_fp8_f32(a.z, a.w, lo, true);
  unsigned hi = __builtin_amdgcn_cvt_pk_fp8_f32(b.x, b.y, 0, false);
  hi = __builtin_amdgcn_cvt_pk_fp8_f32(b.z, b.w, hi, true);
  xq[i] = make_uint2(lo, hi);
}

// Wth layout: [half][COLS][128] bf16. half0=Wl^T, half1=Wr^T.
__global__ void k_prepw(const float* __restrict__ W1l, const float* __restrict__ W1r,
                        const float* __restrict__ W2l, const float* __restrict__ W2r,
                        const float* __restrict__ W3l, const float* __restrict__ W3r,
                        unsigned short* __restrict__ Wth1, unsigned short* __restrict__ Wth2,
                        unsigned short* __restrict__ Wth3) {
  int idx = blockIdx.x * blockDim.x + threadIdx.x;
  if (idx < 32768) {
    int h = idx >> 14, c = (idx >> 7) & 127, k = idx & 127;
    const float* W = h ? W1r : W1l;
    Wth1[idx] = f2bf(W[k * 128 + c]);
  } else if (idx < 65536) {
    int j = idx - 32768;
    int h = j >> 14, c = (j >> 7) & 127, k = j & 127;
    const float* W = h ? W2r : W2l;
    Wth2[j] = f2bf(W[k * 128 + c]);
  } else if (idx < 65536 + 16384) {
    int j = idx - 65536;
    int h = j >> 13, c = (j >> 7) & 63, k = j & 127;
    float v = 0.f;
    if (c < NCLASS) v = (h ? W3r : W3l)[k * NCLASS + c];
    Wth3[j] = f2bf(v);
  }
}

// ---------------- mean aggregation, width 128, fp8 rows (128 B) ----------------
// 8 lanes/row (16 fp8 each), 8 edge-slots per load, 2 loads in flight.
__global__ void k_aggq(const char* __restrict__ Xq, const int* __restrict__ off,
                       const int* __restrict__ col, int n, uint4* __restrict__ out) {
  int wid = (blockIdx.x * blockDim.x + threadIdx.x) >> 6;
  int lane = threadIdx.x & 63;
  if (wid >= n) return;
  int g = lane >> 3, q = lane & 7;
  unsigned qb = (unsigned)q << 4;
  int s = off[wid], e = off[wid + 1];
  float acc[16];
#pragma unroll
  for (int t = 0; t < 16; ++t) acc[t] = 0.f;
  int e1 = e - 1;
  for (int j = s; j < e; j += 16) {
    int i0 = j + g, i1 = i0 + 8;
    int c0 = NTL(&col[min(i0, e1)]);
    int c1 = NTL(&col[min(i1, e1)]);
    float s0 = (i0 < e) ? 1.f : 0.f;
    float s1 = (i1 < e) ? 1.f : 0.f;
    uint4 u0 = *(const uint4*)(Xq + (((unsigned)c0 << 7) + qb));
    uint4 u1 = *(const uint4*)(Xq + (((unsigned)c1 << 7) + qb));
    ACCQ(u0, s0);
    ACCQ(u1, s1);
  }
#pragma unroll
  for (int t = 0; t < 16; ++t) {
    acc[t] += __shfl_xor(acc[t], 8);
    acc[t] += __shfl_xor(acc[t], 16);
    acc[t] += __shfl_xor(acc[t], 32);
  }
  float inv = 1.0f / fmaxf((float)(e - s), 1.0f);
  if (lane < 8) {
    uint4 o0, o1;
    o0.x = (unsigned)f2bf(acc[0] * inv) | ((unsigned)f2bf(acc[1] * inv) << 16);
    o0.y = (unsigned)f2bf(acc[2] * inv) | ((unsigned)f2bf(acc[3] * inv) << 16);
    o0.z = (unsigned)f2bf(acc[4] * inv) | ((unsigned)f2bf(acc[5] * inv) << 16);
    o0.w = (unsigned)f2bf(acc[6] * inv) | ((unsigned)f2bf(acc[7] * inv) << 16);
    o1.x = (unsigned)f2bf(acc[8] * inv) | ((unsigned)f2bf(acc[9] * inv) << 16);
    o1.y = (unsigned)f2bf(acc[10] * inv) | ((unsigned)f2bf(acc[11] * inv) << 16);
    o1.z = (unsigned)f2bf(acc[12] * inv) | ((unsigned)f2bf(acc[13] * inv) << 16);
    o1.w = (unsigned)f2bf(acc[14] * inv) | ((unsigned)f2bf(acc[15] * inv) << 16);
    out[(size_t)wid * 16 + q * 2] = o0;
    out[(size_t)wid * 16 + q * 2 + 1] = o1;
  }
}

// ---------------- MFMA GEMM ----------------
// EPI 0: relu -> outB bf16 [n][128] AND (fp8*)outF [n][128]
// EPI 1: relu -> outB bf16 [n][128] AND outF f32 [n][128]
// EPI 3: cols 0..63 -> (fp8*)outB [n][64] (Y3q); cols 64..127 -> (bf16*)outF [n][64]
template <int COLS, int HALVES, int EPI>
__global__ __launch_bounds__(256) void k_gemm_mfma(
    const unsigned short* __restrict__ Aagg, const unsigned short* __restrict__ Aroot,
    const unsigned short* __restrict__ Wth, const float* __restrict__ bias, int n,
    float* __restrict__ outF, unsigned short* __restrict__ outB) {
  constexpr int RF = 4;
  constexpr int CF = 4;
  __shared__ unsigned short aS[128 * 128];
  __shared__ unsigned short wS[COLS * 128];
  int tid = threadIdx.x;
  int w = tid >> 6, lane = tid & 63, l15 = lane & 15, kg = lane >> 4;
  int rowBase = blockIdx.x * 128;
  int r0 = (w >> 1) * 64;
  int c0 = (w & 1) * 64;

  f32x4 acc[RF][CF];
#pragma unroll
  for (int i = 0; i < RF; ++i)
#pragma unroll
    for (int j = 0; j < CF; ++j) acc[i][j] = (f32x4){0.f, 0.f, 0.f, 0.f};

#pragma unroll
  for (int half = 0; half < HALVES; ++half) {
    if (half) __syncthreads();
    {
      const unsigned short* As = half ? Aroot : Aagg;
#pragma unroll
      for (int it = 0; it < 8; ++it) {
        int row = it * 16 + (tid >> 4);
        int g = rowBase + row;
        g = (g < n) ? g : (n - 1);
        int cb = (tid & 15) << 4;
        int sb = cb ^ ((row & 7) << 4);
        const char* src = (const char*)(As + (size_t)g * 128) + sb;
        char* dst = (char*)aS + it * 4096 + (tid >> 6) * 1024;
        GLOAD_LDS16(src, dst);
      }
      const unsigned short* Ws = Wth + (size_t)half * COLS * 128;
#pragma unroll
      for (int it = 0; it < COLS / 16; ++it) {
        int c = it * 16 + (tid >> 4);
        int cb = (tid & 15) << 4;
        int sb = cb ^ ((c & 7) << 4);
        const char* src = (const char*)(Ws + (size_t)c * 128) + sb;
        char* dst = (char*)wS + it * 4096 + (tid >> 6) * 1024;
        GLOAD_LDS16(src, dst);
      }
      asm volatile("s_waitcnt vmcnt(0)" ::: "memory");
      __syncthreads();
    }
#pragma unroll
    for (int ks = 0; ks < 4; ++ks) {
      int kb = ks * 64 + kg * 16;
      bf16x8 av[RF], bv[CF];
#pragma unroll
      for (int i = 0; i < RF; ++i) {
        int row = r0 + i * 16 + l15;
        av[i] = *(const bf16x8*)((const char*)aS + row * 256 + (kb ^ ((row & 7) << 4)));
      }
#pragma unroll
      for (int j = 0; j < CF; ++j) {
        int c = c0 + j * 16 + l15;
        bv[j] = *(const bf16x8*)((const char*)wS + c * 256 + (kb ^ ((c & 7) << 4)));
      }
#pragma unroll
      for (int i = 0; i < RF; ++i)
#pragma unroll
        for (int j = 0; j < CF; ++j)
          acc[i][j] = __builtin_amdgcn_mfma_f32_16x16x32_bf16(av[i], bv[j], acc[i][j], 0, 0, 0);
    }
  }

  if (EPI == 3) {
    bool leftHalf = (c0 == 0);
    unsigned char* Y3q = (unsigned char*)outB;
    unsigned short* R3b = (unsigned short*)outF;
    float bcol[CF];
#pragma unroll
    for (int j = 0; j < CF; ++j) {
      int c = c0 + j * 16 + l15;
      bcol[j] = (!leftHalf && (c - 64) < NCLASS) ? bias[c - 64] : 0.f;
    }
#pragma unroll
    for (int i = 0; i < RF; ++i) {
#pragma unroll
      for (int r = 0; r < 4; ++r) {
        int row = rowBase + r0 + i * 16 + kg * 4 + r;
        if (row >= n) continue;
#pragma unroll
        for (int j = 0; j < CF; ++j) {
          int c = c0 + j * 16 + l15;
          if (leftHalf) {
            Y3q[(size_t)row * 64 + c] = f2fp8(acc[i][j][r]);
          } else {
            R3b[(size_t)row * 64 + (c - 64)] = f2bf(acc[i][j][r] + bcol[j]);
          }
        }
      }
    }
  } else {
    float bcol[CF];
#pragma unroll
    for (int j = 0; j < CF; ++j) bcol[j] = bias[c0 + j * 16 + l15];
#pragma unroll
    for (int i = 0; i < RF; ++i) {
#pragma unroll
      for (int r = 0; r < 4; ++r) {
        int row = rowBase + r0 + i * 16 + kg * 4 + r;
        if (row >= n) continue;
#pragma unroll
        for (int j = 0; j < CF; ++j) {
          float v = fmaxf(acc[i][j][r] + bcol[j], 0.f);
          int c = c0 + j * 16 + l15;
          outB[(size_t)row * 128 + c] = f2bf(v);
          if (EPI == 1) outF[(size_t)row * 128 + c] = v;
          if (EPI == 0) ((unsigned char*)outF)[(size_t)row * 128 + c] = f2fp8(v);
        }
      }
    }
  }
}

// ---------------- layer-3: width-64 fp8 gather + root + log_softmax ----------------
// Y3q fp8 [n][64] (cols>=40 zero), R3 bf16 [n][64]. 4 lanes/row (16 fp8 each),
// 16 edge-slots per load.
__global__ void k_agg3q(const char* __restrict__ Y3q, const char* __restrict__ R3,
                        const int* __restrict__ off, const int* __restrict__ col, int n,
                        float* __restrict__ out) {
  int wid = (blockIdx.x * blockDim.x + threadIdx.x) >> 6;
  int lane = threadIdx.x & 63;
  if (wid >= n) return;
  int g = lane >> 2, q = lane & 3;
  unsigned qb = (unsigned)q << 4;
  int s = off[wid], e = off[wid + 1];
  float acc[16];
#pragma unroll
  for (int t = 0; t < 16; ++t) acc[t] = 0.f;
  int e1 = e - 1;
  for (int j = s; j < e; j += 16) {
    int i0 = j + g;
    int c0 = NTL(&col[min(i0, e1)]);
    float s0 = (i0 < e) ? 1.f : 0.f;
    uint4 u0 = *(const uint4*)(Y3q + (((unsigned)c0 << 6) + qb));
    ACCQ(u0, s0);
  }
#pragma unroll
  for (int t = 0; t < 16; ++t) {
    acc[t] += __shfl_xor(acc[t], 4);
    acc[t] += __shfl_xor(acc[t], 8);
    acc[t] += __shfl_xor(acc[t], 16);
    acc[t] += __shfl_xor(acc[t], 32);
  }
  float inv = 1.0f / fmaxf((float)(e - s), 1.0f);
  uint4 ur0 = *(const uint4*)(R3 + (((unsigned)wid << 7) + ((unsigned)q << 5)));
  uint4 ur1 = *(const uint4*)(R3 + (((unsigned)wid << 7) + ((unsigned)q << 5) + 16));
  float v[16];
  v[0] = fmaf(acc[0], inv, bflo(ur0.x));
  v[1] = fmaf(acc[1], inv, bfhi(ur0.x));
  v[2] = fmaf(acc[2], inv, bflo(ur0.y));
  v[3] = fmaf(acc[3], inv, bfhi(ur0.y));
  v[4] = fmaf(acc[4], inv, bflo(ur0.z));
  v[5] = fmaf(acc[5], inv, bfhi(ur0.z));
  v[6] = fmaf(acc[6], inv, bflo(ur0.w));
  v[7] = fmaf(acc[7], inv, bfhi(ur0.w));
  v[8] = fmaf(acc[8], inv, bflo(ur1.x));
  v[9] = fmaf(acc[9], inv, bfhi(ur1.x));
  v[10] = fmaf(acc[10], inv, bflo(ur1.y));
  v[11] = fmaf(acc[11], inv, bfhi(ur1.y));
  v[12] = fmaf(acc[12], inv, bflo(ur1.z));
  v[13] = fmaf(acc[13], inv, bfhi(ur1.z));
  v[14] = fmaf(acc[14], inv, bflo(ur1.w));
  v[15] = fmaf(acc[15], inv, bfhi(ur1.w));
  int nv = (q < 2) ? 16 : ((q == 2) ? 8 : 0);
  float m = -INFINITY;
#pragma unroll
  for (int t = 0; t < 16; ++t)
    if (t < nv) m = fmaxf(m, v[t]);
  m = fmaxf(m, __shfl_xor(m, 1));
  m = fmaxf(m, __shfl_xor(m, 2));
  float sum = 0.f;
#pragma unroll
  for (int t = 0; t < 16; ++t)
    if (t < nv) sum += expf(v[t] - m);
  sum += __shfl_xor(sum, 1);
  sum += __shfl_xor(sum, 2);
  float ls = logf(sum);
  if (g == 0 && nv > 0) {
    float* op = out + (size_t)wid * NCLASS + q * 16;
#pragma unroll
    for (int t = 0; t < 16; t += 4) {
      if (t < nv) {
        float4 o = make_float4(v[t] - m - ls, v[t + 1] - m - ls, v[t + 2] - m - ls,
                               v[t + 3] - m - ls);
        *(float4*)(op + t) = o;
      }
    }
  }
}

extern "C" void kernel_launch(void* const* d_in, const int* in_sizes, int n_in,
                              void* d_out, int out_size, void* d_ws, size_t ws_size,
                              hipStream_t stream) {
  const float* x = (const float*)d_in[0];
  const int* ei = (const int*)d_in[1];
  const float* W1l = (const float*)d_in[2];
  const float* b1 = (const float*)d_in[3];
  const float* W1r = (const float*)d_in[4];
  const float* W2l = (const float*)d_in[5];
  const float* b2 = (const float*)d_in[6];
  const float* W2r = (const float*)d_in[7];
  const float* W3l = (const float*)d_in[8];
  const float* b3 = (const float*)d_in[9];
  const float* W3r = (const float*)d_in[10];

  int N = in_sizes[0] / 128;
  int E = in_sizes[1] / 2;
  const int* src = ei;
  const int* dst = ei + E;
  int PART = (N + 7) / 8;
  int nbB = (E + BEDG - 1) / BEDG;
  int CB = (E + 8 * BEDG - 1) / (8 * BEDG);
  if (CB > 256) CB = 256;
  if (CB < 1) CB = 1;

  char* wptr = (char*)d_ws;
  auto alloc = [&](size_t bytes) {
    void* p = (void*)wptr;
    wptr += (bytes + 255) & ~(size_t)255;
    return p;
  };
  int* off = (int*)alloc((size_t)(N + 1) * 4);
  int* col = (int*)alloc((size_t)E * 4);
  int* bcnt = (int*)alloc((size_t)nbB * 8 * 4);
  int* btot = (int*)alloc(16 * 4);
  int* bbase = (int*)alloc(16 * 4);
  int* bcnt2 = (int*)alloc((size_t)8 * CB * 32 * 4);
  int* tot2 = (int*)alloc(256 * 4);
  int* base2 = (int*)alloc(256 * 4);
  unsigned short* Wth1 = (unsigned short*)alloc(32768 * 2);
  unsigned short* Wth2 = (unsigned short*)alloc(32768 * 2);
  unsigned short* Wth3 = (unsigned short*)alloc(16384 * 2);
  unsigned short* xb = (unsigned short*)alloc((size_t)N * 128 * 2);
  unsigned short* mb = (unsigned short*)alloc((size_t)N * 128 * 2);
  unsigned short* h1 = (unsigned short*)alloc((size_t)N * 128 * 2);
  unsigned short* h2 = (unsigned short*)alloc((size_t)N * 128 * 2);
  unsigned char* xq = (unsigned char*)alloc((size_t)N * 128);
  unsigned char* h1q = (unsigned char*)alloc((size_t)N * 128);

  float* outLS = (float*)d_out;                     // [N][40]
  float* emb = (float*)d_out + (size_t)N * NCLASS;  // [N][128]

  // Aliases (lifetimes disjoint on the stream):
  int* ebuf = (int*)h2;       // E ints
  int* ebuf2 = (int*)h2 + E;  // E ints
  unsigned char* Y3q = (unsigned char*)mb;  // fp8 [N][64]; mb dead after gemm2
  unsigned short* R3b = h1;                 // bf16 [N][64]; h1 dead after gemm2

  // CSR build: two-level counting sort, no global atomics
  k_bcount<<<nbB, 256, 0, stream>>>(dst, E, PART, bcnt);
  k_bscanA<<<8, 256, 0, stream>>>(bcnt, nbB, btot);
  k_bbase<<<1, 64, 0, stream>>>(btot, bbase);
  k_place<<<nbB, 256, 0, stream>>>(dst, src, E, PART, bcnt, bbase, ebuf);
  k_bcount2<<<8 * CB, 256, 0, stream>>>(ebuf, bbase, CB, bcnt2);
  k_bscan2<<<256, 256, 0, stream>>>(bcnt2, CB, tot2);
  k_base2<<<1, 64, 0, stream>>>(bbase, tot2, base2);
  k_place2<<<8 * CB, 256, 0, stream>>>(ebuf, bbase, bcnt2, base2, CB, ebuf2);
  k_csr<<<256, 256, 0, stream>>>(ebuf2, base2, tot2, PART, N, E, off, col);

  int n8 = N * 16;
  k_cast<<<(n8 + 255) / 256, 256, 0, stream>>>((const float4*)x, (uint4*)xb, (uint2*)xq,
                                               n8);
  k_prepw<<<(81920 + 255) / 256, 256, 0, stream>>>(W1l, W1r, W2l, W2r, W3l, W3r, Wth1,
                                                   Wth2, Wth3);

  int ab = (N * 64 + 255) / 256;
  int gb = (N + 127) / 128;

  // layer 1: fp8 gather of xq -> mb; gemm writes h1 bf16 + h1q fp8
  k_aggq<<<ab, 256, 0, stream>>>((const char*)xq, off, col, N, (uint4*)mb);
  k_gemm_mfma<128, 2, 0><<<gb, 256, 0, stream>>>(mb, xb, Wth1, b1, N, (float*)h1q, h1);
  // layer 2: fp8 gather of h1q -> mb; gemm writes emb f32 + h2 bf16
  k_aggq<<<ab, 256, 0, stream>>>((const char*)h1q, off, col, N, (uint4*)mb);
  k_gemm_mfma<128, 2, 1><<<gb, 256, 0, stream>>>(mb, h1, Wth2, b2, N, emb, h2);
  // layer 3: project first (Y3q = fp8(h2@W3l), R3 = bf16(h2@W3r + b3)), then
  // width-64 fp8 gather + fused root add + log_softmax
  k_gemm_mfma<128, 1, 3><<<gb, 256, 0, stream>>>(h2, nullptr, Wth3, b3, N, (float*)R3b,
                                                 (unsigned short*)Y3q);
  k_agg3q<<<ab, 256, 0, stream>>>((const char*)Y3q, (const char*)R3b, off, col, N, outLS);
}

// Round 9
// 303.073 us; speedup vs baseline: 1.1076x; 1.1076x over previous
//
#include <hip/hip_runtime.h>
#include <math.h>

#define NCLASS 40
#define BEDG4 4096  // edges per chunk block in CSR build
#define CAP 24576   // LDS col-staging capacity per 512-node sub-bucket

typedef float f32x4 __attribute__((ext_vector_type(4)));
typedef float f32x2 __attribute__((ext_vector_type(2)));
typedef __bf16 bf16x8 __attribute__((ext_vector_type(8)));

typedef __attribute__((address_space(1))) const void gv_t;
typedef __attribute__((address_space(3))) void lv_t;
#define GLOAD_LDS16(g, l) __builtin_amdgcn_global_load_lds((gv_t*)(g), (lv_t*)(l), 16, 0, 0)
#define NTL(p) __builtin_nontemporal_load(p)

__device__ inline unsigned short f2bf(float f) {
  unsigned u = __float_as_uint(f);
  unsigned r = (u + 0x7fff + ((u >> 16) & 1)) >> 16;
  return (unsigned short)r;
}
__device__ inline float bflo(unsigned v) { return __uint_as_float(v << 16); }
__device__ inline float bfhi(unsigned v) { return __uint_as_float(v & 0xffff0000u); }

// decode 16 fp8 (one uint4) and accumulate with scale
#define ACCQ(u, sc)                                                                  \
  do {                                                                               \
    f32x2 p_;                                                                        \
    p_ = __builtin_amdgcn_cvt_pk_f32_fp8(u.x, false);                                \
    acc[0] = fmaf(p_.x, sc, acc[0]); acc[1] = fmaf(p_.y, sc, acc[1]);                \
    p_ = __builtin_amdgcn_cvt_pk_f32_fp8(u.x, true);                                 \
    acc[2] = fmaf(p_.x, sc, acc[2]); acc[3] = fmaf(p_.y, sc, acc[3]);                \
    p_ = __builtin_amdgcn_cvt_pk_f32_fp8(u.y, false);                                \
    acc[4] = fmaf(p_.x, sc, acc[4]); acc[5] = fmaf(p_.y, sc, acc[5]);                \
    p_ = __builtin_amdgcn_cvt_pk_f32_fp8(u.y, true);                                 \
    acc[6] = fmaf(p_.x, sc, acc[6]); acc[7] = fmaf(p_.y, sc, acc[7]);                \
    p_ = __builtin_amdgcn_cvt_pk_f32_fp8(u.z, false);                                \
    acc[8] = fmaf(p_.x, sc, acc[8]); acc[9] = fmaf(p_.y, sc, acc[9]);                \
    p_ = __builtin_amdgcn_cvt_pk_f32_fp8(u.z, true);                                 \
    acc[10] = fmaf(p_.x, sc, acc[10]); acc[11] = fmaf(p_.y, sc, acc[11]);            \
    p_ = __builtin_amdgcn_cvt_pk_f32_fp8(u.w, false);                                \
    acc[12] = fmaf(p_.x, sc, acc[12]); acc[13] = fmaf(p_.y, sc, acc[13]);            \
    p_ = __builtin_amdgcn_cvt_pk_f32_fp8(u.w, true);                                 \
    acc[14] = fmaf(p_.x, sc, acc[14]); acc[15] = fmaf(p_.y, sc, acc[15]);            \
  } while (0)

// ============ CSR build: single-level counting sort by 512-node range =========
// sub-bucket sb = dst >> 9 (NSB = ceil(N/512) <= 256). Packed record:
// (dstLocal9 << 17) | src17.

// pass 1: per-4096-edge chunk sub-bucket counts (LDS counters)
__global__ __launch_bounds__(256) void k_bcountF(const int* __restrict__ dst, int E,
                                                 int* __restrict__ bcnt) {
  __shared__ int lc[256];
  int k = blockIdx.x;
  int tid = threadIdx.x;
  lc[tid] = 0;
  __syncthreads();
  int lo = k * BEDG4, hi = min(lo + BEDG4, E);
  for (int i = lo + tid; i < hi; i += 256) atomicAdd(&lc[NTL(&dst[i]) >> 9], 1);
  __syncthreads();
  bcnt[k * 256 + tid] = lc[tid];
}

// pass 2: one block per sub-bucket, exclusive scan over chunk counts
__global__ __launch_bounds__(256) void k_bscanF(int* __restrict__ bcnt, int nbB,
                                                int* __restrict__ tot) {
  __shared__ int tmp[256];
  __shared__ int carryS;
  int b = blockIdx.x;
  int tid = threadIdx.x;
  if (tid == 0) carryS = 0;
  __syncthreads();
  for (int c0 = 0; c0 < nbB; c0 += 256) {
    int idx = c0 + tid;
    int v = (idx < nbB) ? bcnt[idx * 256 + b] : 0;
    tmp[tid] = v;
    __syncthreads();
    for (int d = 1; d < 256; d <<= 1) {
      int t = (tid >= d) ? tmp[tid - d] : 0;
      __syncthreads();
      tmp[tid] += t;
      __syncthreads();
    }
    if (idx < nbB) bcnt[idx * 256 + b] = carryS + tmp[tid] - v;
    __syncthreads();
    if (tid == 255) carryS += tmp[255];
    __syncthreads();
  }
  if (tid == 0) tot[b] = carryS;
}

// pass 3: sub-bucket bases (single block), also off[N]=E
__global__ __launch_bounds__(256) void k_baseF(const int* __restrict__ tot, int NSB,
                                               int N, int E, int* __restrict__ base2,
                                               int* __restrict__ off) {
  __shared__ int tmp[256];
  int tid = threadIdx.x;
  int v = (tid < NSB) ? tot[tid] : 0;
  tmp[tid] = v;
  __syncthreads();
  for (int d = 1; d < 256; d <<= 1) {
    int t = (tid >= d) ? tmp[tid - d] : 0;
    __syncthreads();
    tmp[tid] += t;
    __syncthreads();
  }
  base2[tid] = tmp[tid] - v;
  if (tid == 0) {
    base2[NSB] = E;
    off[N] = E;
  }
}

// pass 4: place packed records sub-bucket-contiguous
__global__ __launch_bounds__(256) void k_placeF(const int* __restrict__ dst,
                                                const int* __restrict__ src, int E,
                                                const int* __restrict__ bcnt,
                                                const int* __restrict__ base2,
                                                int* __restrict__ ebuf2) {
  __shared__ int lb[256];
  int k = blockIdx.x;
  int tid = threadIdx.x;
  lb[tid] = base2[tid] + bcnt[k * 256 + tid];
  __syncthreads();
  int lo = k * BEDG4, hi = min(lo + BEDG4, E);
  for (int i = lo + tid; i < hi; i += 256) {
    int d = NTL(&dst[i]);
    int s = NTL(&src[i]);
    int pos = atomicAdd(&lb[d >> 9], 1);
    ebuf2[pos] = (int)(((unsigned)(d & 511) << 17) | (unsigned)s);
  }
}

// pass 5: one block per sub-bucket; CSR slice built in LDS, col written coalesced
__global__ __launch_bounds__(256) void k_csrF(const int* __restrict__ ebuf2,
                                              const int* __restrict__ base2,
                                              const int* __restrict__ tot, int N,
                                              int* __restrict__ off,
                                              int* __restrict__ col) {
  __shared__ int cnt[512];
  __shared__ int cur[512];
  __shared__ int tmp[256];
  __shared__ int stage[CAP];
  int sb = blockIdx.x;
  int tid = threadIdx.x;
  int node0 = sb << 9;
  if (node0 >= N) return;
  int nn = min(512, N - node0);
  int lo = base2[sb];
  int t2 = tot[sb];

  cnt[tid] = 0;
  cnt[tid + 256] = 0;
  __syncthreads();
  for (int i = lo + tid; i < lo + t2; i += 256)
    atomicAdd(&cnt[(((unsigned)ebuf2[i]) >> 17) & 511], 1);
  __syncthreads();

  int v0 = cnt[2 * tid], v1 = cnt[2 * tid + 1];
  int s = v0 + v1;
  tmp[tid] = s;
  __syncthreads();
  for (int d = 1; d < 256; d <<= 1) {
    int t = (tid >= d) ? tmp[tid - d] : 0;
    __syncthreads();
    tmp[tid] += t;
    __syncthreads();
  }
  int excl = tmp[tid] - s;
  cnt[2 * tid] = excl;
  cnt[2 * tid + 1] = excl + v0;
  cur[2 * tid] = excl;
  cur[2 * tid + 1] = excl + v0;
  __syncthreads();

  for (int i = tid; i < nn; i += 256) off[node0 + i] = lo + cnt[i];

  if (t2 <= CAP) {
    for (int i = lo + tid; i < lo + t2; i += 256) {
      unsigned pk = (unsigned)ebuf2[i];
      int pos = atomicAdd(&cur[(pk >> 17) & 511], 1);
      stage[pos] = (int)(pk & 0x1FFFFu);
    }
    __syncthreads();
    for (int i = tid; i < t2; i += 256) col[lo + i] = stage[i];
  } else {
    for (int i = lo + tid; i < lo + t2; i += 256) {
      unsigned pk = (unsigned)ebuf2[i];
      int pos = atomicAdd(&cur[(pk >> 17) & 511], 1);
      col[lo + pos] = (int)(pk & 0x1FFFFu);
    }
  }
}

// ---------------- casts / weight prep ----------------
__global__ void k_cast(const float4* __restrict__ x, uint4* __restrict__ xb,
                       uint2* __restrict__ xq, int n8) {
  int i = blockIdx.x * blockDim.x + threadIdx.x;
  if (i >= n8) return;
  float4 a = x[i * 2], b = x[i * 2 + 1];
  uint4 o;
  o.x = (unsigned)f2bf(a.x) | ((unsigned)f2bf(a.y) << 16);
  o.y = (unsigned)f2bf(a.z) | ((unsigned)f2bf(a.w) << 16);
  o.z = (unsigned)f2bf(b.x) | ((unsigned)f2bf(b.y) << 16);
  o.w = (unsigned)f2bf(b.z) | ((unsigned)f2bf(b.w) << 16);
  xb[i] = o;
  unsigned lo = __builtin_amdgcn_cvt_pk_fp8_f32(a.x, a.y, 0, false);
  lo = __builtin_amdgcn_cvt_pk_fp8_f32(a.z, a.w, lo, true);
  unsigned hi = __builtin_amdgcn_cvt_pk_fp8_f32(b.x, b.y, 0, false);
  hi = __builtin_amdgcn_cvt_pk_fp8_f32(b.z, b.w, hi, true);
  xq[i] = make_uint2(lo, hi);
}

// Wth layout: [half][COLS][128] bf16. half0=Wl^T, half1=Wr^T.
__global__ void k_prepw(const float* __restrict__ W1l, const float* __restrict__ W1r,
                        const float* __restrict__ W2l, const float* __restrict__ W2r,
                        const float* __restrict__ W3l, const float* __restrict__ W3r,
                        unsigned short* __restrict__ Wth1, unsigned short* __restrict__ Wth2,
                        unsigned short* __restrict__ Wth3) {
  int idx = blockIdx.x * blockDim.x + threadIdx.x;
  if (idx < 32768) {
    int h = idx >> 14, c = (idx >> 7) & 127, k = idx & 127;
    const float* W = h ? W1r : W1l;
    Wth1[idx] = f2bf(W[k * 128 + c]);
  } else if (idx < 65536) {
    int j = idx - 32768;
    int h = j >> 14, c = (j >> 7) & 127, k = j & 127;
    const float* W = h ? W2r : W2l;
    Wth2[j] = f2bf(W[k * 128 + c]);
  } else if (idx < 65536 + 16384) {
    int j = idx - 65536;
    int h = j >> 13, c = (j >> 7) & 63, k = j & 127;
    float v = 0.f;
    if (c < NCLASS) v = (h ? W3r : W3l)[k * NCLASS + c];
    Wth3[j] = f2bf(v);
  }
}

// ---------------- mean aggregation, width 128, fp8 rows (128 B) ----------------
// 8 lanes/row (16 fp8 each), 8 edge-slots per load, 2 loads in flight.
__global__ void k_aggq(const char* __restrict__ Xq, const int* __restrict__ off,
                       const int* __restrict__ col, int n, uint4* __restrict__ out) {
  int wid = (blockIdx.x * blockDim.x + threadIdx.x) >> 6;
  int lane = threadIdx.x & 63;
  if (wid >= n) return;
  int g = lane >> 3, q = lane & 7;
  unsigned qb = (unsigned)q << 4;
  int s = off[wid], e = off[wid + 1];
  float acc[16];
#pragma unroll
  for (int t = 0; t < 16; ++t) acc[t] = 0.f;
  int e1 = e - 1;
  for (int j = s; j < e; j += 16) {
    int i0 = j + g, i1 = i0 + 8;
    int c0 = NTL(&col[min(i0, e1)]);
    int c1 = NTL(&col[min(i1, e1)]);
    float s0 = (i0 < e) ? 1.f : 0.f;
    float s1 = (i1 < e) ? 1.f : 0.f;
    uint4 u0 = *(const uint4*)(Xq + (((unsigned)c0 << 7) + qb));
    uint4 u1 = *(const uint4*)(Xq + (((unsigned)c1 << 7) + qb));
    ACCQ(u0, s0);
    ACCQ(u1, s1);
  }
#pragma unroll
  for (int t = 0; t < 16; ++t) {
    acc[t] += __shfl_xor(acc[t], 8);
    acc[t] += __shfl_xor(acc[t], 16);
    acc[t] += __shfl_xor(acc[t], 32);
  }
  float inv = 1.0f / fmaxf((float)(e - s), 1.0f);
  if (lane < 8) {
    uint4 o0, o1;
    o0.x = (unsigned)f2bf(acc[0] * inv) | ((unsigned)f2bf(acc[1] * inv) << 16);
    o0.y = (unsigned)f2bf(acc[2] * inv) | ((unsigned)f2bf(acc[3] * inv) << 16);
    o0.z = (unsigned)f2bf(acc[4] * inv) | ((unsigned)f2bf(acc[5] * inv) << 16);
    o0.w = (unsigned)f2bf(acc[6] * inv) | ((unsigned)f2bf(acc[7] * inv) << 16);
    o1.x = (unsigned)f2bf(acc[8] * inv) | ((unsigned)f2bf(acc[9] * inv) << 16);
    o1.y = (unsigned)f2bf(acc[10] * inv) | ((unsigned)f2bf(acc[11] * inv) << 16);
    o1.z = (unsigned)f2bf(acc[12] * inv) | ((unsigned)f2bf(acc[13] * inv) << 16);
    o1.w = (unsigned)f2bf(acc[14] * inv) | ((unsigned)f2bf(acc[15] * inv) << 16);
    out[(size_t)wid * 16 + q * 2] = o0;
    out[(size_t)wid * 16 + q * 2 + 1] = o1;
  }
}

// ---------------- MFMA GEMM ----------------
// EPI 0: relu -> outB bf16 [n][128] AND (fp8*)outF [n][128]
// EPI 1: relu -> outB bf16 [n][128] AND outF f32 [n][128]
// EPI 3: cols 0..63 -> outB bf16 [n][64] (Y3); cols 64..127 -> (bf16*)outF [n][64] (R3)
template <int COLS, int HALVES, int EPI>
__global__ __launch_bounds__(256) void k_gemm_mfma(
    const unsigned short* __restrict__ Aagg, const unsigned short* __restrict__ Aroot,
    const unsigned short* __restrict__ Wth, const float* __restrict__ bias, int n,
    float* __restrict__ outF, unsigned short* __restrict__ outB) {
  constexpr int RF = 4;
  constexpr int CF = 4;
  __shared__ unsigned short aS[128 * 128];
  __shared__ unsigned short wS[COLS * 128];
  int tid = threadIdx.x;
  int w = tid >> 6, lane = tid & 63, l15 = lane & 15, kg = lane >> 4;
  int rowBase = blockIdx.x * 128;
  int r0 = (w >> 1) * 64;
  int c0 = (w & 1) * 64;

  f32x4 acc[RF][CF];
#pragma unroll
  for (int i = 0; i < RF; ++i)
#pragma unroll
    for (int j = 0; j < CF; ++j) acc[i][j] = (f32x4){0.f, 0.f, 0.f, 0.f};

#pragma unroll
  for (int half = 0; half < HALVES; ++half) {
    if (half) __syncthreads();
    {
      const unsigned short* As = half ? Aroot : Aagg;
#pragma unroll
      for (int it = 0; it < 8; ++it) {
        int row = it * 16 + (tid >> 4);
        int g = rowBase + row;
        g = (g < n) ? g : (n - 1);
        int cb = (tid & 15) << 4;
        int sb = cb ^ ((row & 7) << 4);
        const char* src = (const char*)(As + (size_t)g * 128) + sb;
        char* dst = (char*)aS + it * 4096 + (tid >> 6) * 1024;
        GLOAD_LDS16(src, dst);
      }
      const unsigned short* Ws = Wth + (size_t)half * COLS * 128;
#pragma unroll
      for (int it = 0; it < COLS / 16; ++it) {
        int c = it * 16 + (tid >> 4);
        int cb = (tid & 15) << 4;
        int sb = cb ^ ((c & 7) << 4);
        const char* src = (const char*)(Ws + (size_t)c * 128) + sb;
        char* dst = (char*)wS + it * 4096 + (tid >> 6) * 1024;
        GLOAD_LDS16(src, dst);
      }
      asm volatile("s_waitcnt vmcnt(0)" ::: "memory");
      __syncthreads();
    }
#pragma unroll
    for (int ks = 0; ks < 4; ++ks) {
      int kb = ks * 64 + kg * 16;
      bf16x8 av[RF], bv[CF];
#pragma unroll
      for (int i = 0; i < RF; ++i) {
        int row = r0 + i * 16 + l15;
        av[i] = *(const bf16x8*)((const char*)aS + row * 256 + (kb ^ ((row & 7) << 4)));
      }
#pragma unroll
      for (int j = 0; j < CF; ++j) {
        int c = c0 + j * 16 + l15;
        bv[j] = *(const bf16x8*)((const char*)wS + c * 256 + (kb ^ ((c & 7) << 4)));
      }
#pragma unroll
      for (int i = 0; i < RF; ++i)
#pragma unroll
        for (int j = 0; j < CF; ++j)
          acc[i][j] = __builtin_amdgcn_mfma_f32_16x16x32_bf16(av[i], bv[j], acc[i][j], 0, 0, 0);
    }
  }

  if (EPI == 3) {
    bool leftHalf = (c0 == 0);
    unsigned short* R3b = (unsigned short*)outF;
    float bcol[CF];
#pragma unroll
    for (int j = 0; j < CF; ++j) {
      int c = c0 + j * 16 + l15;
      bcol[j] = (!leftHalf && (c - 64) < NCLASS) ? bias[c - 64] : 0.f;
    }
#pragma unroll
    for (int i = 0; i < RF; ++i) {
#pragma unroll
      for (int r = 0; r < 4; ++r) {
        int row = rowBase + r0 + i * 16 + kg * 4 + r;
        if (row >= n) continue;
#pragma unroll
        for (int j = 0; j < CF; ++j) {
          int c = c0 + j * 16 + l15;
          if (leftHalf) {
            outB[(size_t)row * 64 + c] = f2bf(acc[i][j][r]);
          } else {
            R3b[(size_t)row * 64 + (c - 64)] = f2bf(acc[i][j][r] + bcol[j]);
          }
        }
      }
    }
  } else {
    float bcol[CF];
#pragma unroll
    for (int j = 0; j < CF; ++j) bcol[j] = bias[c0 + j * 16 + l15];
#pragma unroll
    for (int i = 0; i < RF; ++i) {
#pragma unroll
      for (int r = 0; r < 4; ++r) {
        int row = rowBase + r0 + i * 16 + kg * 4 + r;
        if (row >= n) continue;
#pragma unroll
        for (int j = 0; j < CF; ++j) {
          float v = fmaxf(acc[i][j][r] + bcol[j], 0.f);
          int c = c0 + j * 16 + l15;
          outB[(size_t)row * 128 + c] = f2bf(v);
          if (EPI == 1) outF[(size_t)row * 128 + c] = v;
          if (EPI == 0) {
            unsigned pk = __builtin_amdgcn_cvt_pk_fp8_f32(v, v, 0, false);
            ((unsigned char*)outF)[(size_t)row * 128 + c] = (unsigned char)(pk & 0xff);
          }
        }
      }
    }
  }
}

// ---------------- layer-3: width-64 bf16 mean agg + root + log_softmax ----------------
#define ACC8(u, sc)                          \
  acc[0] = fmaf(bflo(u.x), sc, acc[0]);      \
  acc[1] = fmaf(bfhi(u.x), sc, acc[1]);      \
  acc[2] = fmaf(bflo(u.y), sc, acc[2]);      \
  acc[3] = fmaf(bfhi(u.y), sc, acc[3]);      \
  acc[4] = fmaf(bflo(u.z), sc, acc[4]);      \
  acc[5] = fmaf(bfhi(u.z), sc, acc[5]);      \
  acc[6] = fmaf(bflo(u.w), sc, acc[6]);      \
  acc[7] = fmaf(bfhi(u.w), sc, acc[7]);

__global__ void k_agg3ls(const char* __restrict__ Y3, const char* __restrict__ R3,
                         const int* __restrict__ off, const int* __restrict__ col, int n,
                         float* __restrict__ out) {
  int wid = (blockIdx.x * blockDim.x + threadIdx.x) >> 6;
  int lane = threadIdx.x & 63;
  if (wid >= n) return;
  int g = lane >> 3, q = lane & 7;
  unsigned qb = (unsigned)q << 4;
  int s = off[wid], e = off[wid + 1];
  float acc[8];
#pragma unroll
  for (int t = 0; t < 8; ++t) acc[t] = 0.f;
  int e1 = e - 1;
  for (int j = s; j < e; j += 16) {
    int i0 = j + g, i1 = i0 + 8;
    int c0 = NTL(&col[min(i0, e1)]);
    int c1 = NTL(&col[min(i1, e1)]);
    float s0 = (i0 < e) ? 1.f : 0.f;
    float s1 = (i1 < e) ? 1.f : 0.f;
    uint4 u0 = *(const uint4*)(Y3 + (((unsigned)c0 << 7) + qb));
    uint4 u1 = *(const uint4*)(Y3 + (((unsigned)c1 << 7) + qb));
    ACC8(u0, s0);
    ACC8(u1, s1);
  }
#pragma unroll
  for (int t = 0; t < 8; ++t) {
    acc[t] += __shfl_xor(acc[t], 8);
    acc[t] += __shfl_xor(acc[t], 16);
    acc[t] += __shfl_xor(acc[t], 32);
  }
  float inv = 1.0f / fmaxf((float)(e - s), 1.0f);
  uint4 ur = *(const uint4*)(R3 + (((unsigned)wid << 7) + qb));
  float v[8];
  v[0] = fmaf(acc[0], inv, bflo(ur.x));
  v[1] = fmaf(acc[1], inv, bfhi(ur.x));
  v[2] = fmaf(acc[2], inv, bflo(ur.y));
  v[3] = fmaf(acc[3], inv, bfhi(ur.y));
  v[4] = fmaf(acc[4], inv, bflo(ur.z));
  v[5] = fmaf(acc[5], inv, bfhi(ur.z));
  v[6] = fmaf(acc[6], inv, bflo(ur.w));
  v[7] = fmaf(acc[7], inv, bfhi(ur.w));
  bool valid = q < 5;  // cols q*8..q*8+7 < 40
  float m = -INFINITY;
  if (valid) {
#pragma unroll
    for (int t = 0; t < 8; ++t) m = fmaxf(m, v[t]);
  }
  m = fmaxf(m, __shfl_xor(m, 1));
  m = fmaxf(m, __shfl_xor(m, 2));
  m = fmaxf(m, __shfl_xor(m, 4));
  float sum = 0.f;
  if (valid) {
#pragma unroll
    for (int t = 0; t < 8; ++t) sum += expf(v[t] - m);
  }
  sum += __shfl_xor(sum, 1);
  sum += __shfl_xor(sum, 2);
  sum += __shfl_xor(sum, 4);
  float ls = logf(sum);
  if (lane < 5) {
    float4 o0 = make_float4(v[0] - m - ls, v[1] - m - ls, v[2] - m - ls, v[3] - m - ls);
    float4 o1 = make_float4(v[4] - m - ls, v[5] - m - ls, v[6] - m - ls, v[7] - m - ls);
    float* op = out + (size_t)wid * NCLASS + lane * 8;
    *(float4*)op = o0;
    *(float4*)(op + 4) = o1;
  }
}

extern "C" void kernel_launch(void* const* d_in, const int* in_sizes, int n_in,
                              void* d_out, int out_size, void* d_ws, size_t ws_size,
                              hipStream_t stream) {
  const float* x = (const float*)d_in[0];
  const int* ei = (const int*)d_in[1];
  const float* W1l = (const float*)d_in[2];
  const float* b1 = (const float*)d_in[3];
  const float* W1r = (const float*)d_in[4];
  const float* W2l = (const float*)d_in[5];
  const float* b2 = (const float*)d_in[6];
  const float* W2r = (const float*)d_in[7];
  const float* W3l = (const float*)d_in[8];
  const float* b3 = (const float*)d_in[9];
  const float* W3r = (const float*)d_in[10];

  int N = in_sizes[0] / 128;
  int E = in_sizes[1] / 2;
  const int* src = ei;
  const int* dst = ei + E;
  int NSB = (N + 511) >> 9;  // <= 256 for N <= 131072
  int nbB = (E + BEDG4 - 1) / BEDG4;

  char* wptr = (char*)d_ws;
  auto alloc = [&](size_t bytes) {
    void* p = (void*)wptr;
    wptr += (bytes + 255) & ~(size_t)255;
    return p;
  };
  int* off = (int*)alloc((size_t)(N + 1) * 4);
  int* col = (int*)alloc((size_t)E * 4);
  int* bcnt = (int*)alloc((size_t)nbB * 256 * 4);
  int* tot = (int*)alloc(256 * 4);
  int* base2 = (int*)alloc(257 * 4);
  unsigned short* Wth1 = (unsigned short*)alloc(32768 * 2);
  unsigned short* Wth2 = (unsigned short*)alloc(32768 * 2);
  unsigned short* Wth3 = (unsigned short*)alloc(16384 * 2);
  unsigned short* xb = (unsigned short*)alloc((size_t)N * 128 * 2);
  unsigned short* mb = (unsigned short*)alloc((size_t)N * 128 * 2);
  unsigned short* h1 = (unsigned short*)alloc((size_t)N * 128 * 2);
  unsigned short* h2 = (unsigned short*)alloc((size_t)N * 128 * 2);
  unsigned char* xq = (unsigned char*)alloc((size_t)N * 128);
  unsigned char* h1q = (unsigned char*)alloc((size_t)N * 128);

  float* outLS = (float*)d_out;                     // [N][40]
  float* emb = (float*)d_out + (size_t)N * NCLASS;  // [N][128]

  // Aliases (lifetimes disjoint on the stream):
  int* ebuf2 = (int*)h2;     // E ints; dead before gemm2 writes h2
  unsigned short* Y3 = mb;   // bf16 [N][64]; mb dead after gemm2
  unsigned short* R3b = h1;  // bf16 [N][64]; h1 dead after gemm2

  // CSR build: single-level counting sort by 512-node range, no global atomics
  k_bcountF<<<nbB, 256, 0, stream>>>(dst, E, bcnt);
  k_bscanF<<<NSB, 256, 0, stream>>>(bcnt, nbB, tot);
  k_baseF<<<1, 256, 0, stream>>>(tot, NSB, N, E, base2, off);
  k_placeF<<<nbB, 256, 0, stream>>>(dst, src, E, bcnt, base2, ebuf2);
  k_csrF<<<NSB, 256, 0, stream>>>(ebuf2, base2, tot, N, off, col);

  int n8 = N * 16;
  k_cast<<<(n8 + 255) / 256, 256, 0, stream>>>((const float4*)x, (uint4*)xb, (uint2*)xq,
                                               n8);
  k_prepw<<<(81920 + 255) / 256, 256, 0, stream>>>(W1l, W1r, W2l, W2r, W3l, W3r, Wth1,
                                                   Wth2, Wth3);

  int ab = (N * 64 + 255) / 256;
  int gb = (N + 127) / 128;

  // layer 1: fp8 gather of xq -> mb; gemm writes h1 bf16 + h1q fp8
  k_aggq<<<ab, 256, 0, stream>>>((const char*)xq, off, col, N, (uint4*)mb);
  k_gemm_mfma<128, 2, 0><<<gb, 256, 0, stream>>>(mb, xb, Wth1, b1, N, (float*)h1q, h1);
  // layer 2: fp8 gather of h1q -> mb; gemm writes emb f32 + h2 bf16
  k_aggq<<<ab, 256, 0, stream>>>((const char*)h1q, off, col, N, (uint4*)mb);
  k_gemm_mfma<128, 2, 1><<<gb, 256, 0, stream>>>(mb, h1, Wth2, b2, N, emb, h2);
  // layer 3: project first (Y3 = h2@W3l bf16, R3 = h2@W3r + b3 bf16), then
  // width-64 bf16 gather + fused root add + log_softmax
  k_gemm_mfma<128, 1, 3><<<gb, 256, 0, stream>>>(h2, nullptr, Wth3, b3, N, (float*)R3b, Y3);
  k_agg3ls<<<ab, 256, 0, stream>>>((const char*)Y3, (const char*)R3b, off, col, N, outLS);
}